// Round 6
// baseline (399.586 us; speedup 1.0000x reference)
//
#include <hip/hip_runtime.h>
#include <math.h>
#include <stdint.h>

// Problem constants (fixed by the reference)
#define NPTS 500000
#define SCALE 0.35355339059327373f   // 1/sqrt(8)
#define NT128 3907                   // ceil(500000/128)
#define TPB 4                        // 128-pt tiles per block
#define GRID ((NT128 + TPB - 1) / TPB)
#define Q4TOT 8000000                // NPTS*16 float4's in q / e / out

// ws layout (float offsets):
// [8192,8704)   khs[b][c] = (k@Wk.T + bk)*scale
// [8704,9216)   vh[b][c]  = v@Wv.T + bv
// [9216,10240)  z as double[512]

// ---------------------------------------------------------------------------
// Swizzled-linear tile addressing (both A tiles and W tiles):
//   tile is [row][16 float4-chunks]; slot sc of row r holds k-quad sc ^ X(r),
//   X(r) = (r>>3)&7 for A (conflicting lanes differ in bits 3..5 of r),
//   X(c) = (c>>2)&7 for W (conflicting lanes differ in bits 2..4 of c).
// Read index:  tile4[(r*16 | X(r)) ^ kq]  -> distinct bank-quads across lanes.
// Stage (A):   global_load_lds linear dest; per-lane SOURCE pre-swizzled with
//              the same involution (rule #21: both-sides-or-neither).
// ---------------------------------------------------------------------------

__device__ __forceinline__ void gload_lds16(const float* g, float* l) {
    __builtin_amdgcn_global_load_lds(
        (const __attribute__((address_space(1))) void*)g,
        (__attribute__((address_space(3))) void*)l, 16, 0, 0);
}

// async-stage a 128x64 f32 tile (rows = points) from gsrc into swizzled LDS.
__device__ __forceinline__ void stage_tile_async(const float* __restrict__ gsrc,
                                                 int t, float* lds, int tid) {
    const int wv   = tid >> 6;
    const int ln   = tid & 63;
    const int lrow = ln >> 4;    // 4 rows per 1KB chunk
    const int j    = ln & 15;
    #pragma unroll
    for (int qi = 0; qi < 16; ++qi) {
        const int chunk = wv * 16 + qi;          // 0..31 (1KB each)
        const int row   = chunk * 4 + lrow;      // 0..127
        int g4 = t * 2048 + row * 16 + (j ^ ((row >> 3) & 7));
        if (g4 >= Q4TOT) g4 = 0;                 // safe clamp; epilogue masks OOB pts
        gload_lds16(gsrc + (size_t)g4 * 4, lds + chunk * 256);
    }
}

__global__ void prep_kernel(const float* __restrict__ kin, const float* __restrict__ vin,
                            const float* __restrict__ Wk, const float* __restrict__ bk,
                            const float* __restrict__ Wv, const float* __restrict__ bv,
                            float* __restrict__ ws) {
    const int gid = blockIdx.x * 256 + threadIdx.x;
    float* khs = ws + 8192;
    float* vh  = ws + 8704;
    double* zg = (double*)(ws + 9216);
    for (int idx = gid; idx < 512; idx += 8 * 256) {
        int b = idx >> 6, c = idx & 63;
        float dk = 0.f, dv = 0.f;
        #pragma unroll 8
        for (int j = 0; j < 64; ++j) {
            dk = fmaf(kin[b * 64 + j], Wk[c * 64 + j], dk);
            dv = fmaf(vin[b * 64 + j], Wv[c * 64 + j], dv);
        }
        khs[idx] = (dk + bk[c]) * SCALE;
        vh[idx]  = dv + bv[c];
        zg[idx]  = 0.0;
    }
}

// Thread mapping (both passes): 128 threads. cc = tid&7 -> channels {4cc..+3, 32+4cc..+3};
// ty = tid>>3 (0..15) -> points 8ty..8ty+7. acc[8][8]: per k-quad 16 reads feed 256 FMAs.

#define GEMM88(TILE4, W4)                                                    \
    _Pragma("unroll 4")                                                      \
    for (int kq = 0; kq < 16; ++kq) {                                        \
        float4 av[8], wv[8];                                                 \
        _Pragma("unroll")                                                    \
        for (int i = 0; i < 8; ++i) av[i] = (TILE4)[ab[i] ^ kq];             \
        _Pragma("unroll")                                                    \
        for (int m = 0; m < 8; ++m) wv[m] = (W4)[wb[m] ^ kq];                \
        _Pragma("unroll")                                                    \
        for (int i = 0; i < 8; ++i) {                                        \
            _Pragma("unroll")                                                \
            for (int m = 0; m < 8; ++m) {                                    \
                acc[i][m] = fmaf(av[i].x, wv[m].x, acc[i][m]);               \
                acc[i][m] = fmaf(av[i].y, wv[m].y, acc[i][m]);               \
                acc[i][m] = fmaf(av[i].z, wv[m].z, acc[i][m]);               \
                acc[i][m] = fmaf(av[i].w, wv[m].w, acc[i][m]);               \
            }                                                                \
        }                                                                    \
    }

#define SETUP_BASES()                                                        \
    int ab[8], wb[8];                                                        \
    {                                                                        \
        const int tyx = ty & 7;                                              \
        _Pragma("unroll")                                                    \
        for (int i = 0; i < 8; ++i) ab[i] = ((8 * ty + i) * 16) | tyx;       \
        _Pragma("unroll")                                                    \
        for (int m = 0; m < 4; ++m) {                                        \
            wb[m]     = ((4 * cc + m) * 16) | cc;                            \
            wb[4 + m] = ((32 + 4 * cc + m) * 16) | cc;                       \
        }                                                                    \
    }

// passA: e = exp((q@Wq.T + bq) * khs[batch]) -> e_out (aliases d_out), z-accum (f64 global)
__global__ __launch_bounds__(128, 2) void passA_kernel(const float* __restrict__ q,
                                                       const int* __restrict__ batch,
                                                       const float* __restrict__ bq,
                                                       const float* __restrict__ Wq,
                                                       float* __restrict__ ws,
                                                       float* __restrict__ e_out) {
    __shared__ __align__(16) float qT[8192];     // 128x64, swizzled-linear
    __shared__ __align__(16) float wq[4096];     // 64x64, swizzled-linear
    __shared__ __align__(16) float khs_l[512];
    __shared__ __align__(16) float zred[128];

    const float* khs_g = ws + 8192;
    double* zg = (double*)(ws + 9216);

    const int tid = threadIdx.x;
    const int cc  = tid & 7;
    const int ty  = tid >> 3;

    const float4* qT4 = (const float4*)qT;
    const float4* wq4c = (const float4*)wq;
    float4* wq4 = (float4*)wq;

    // one-time: stage Wq (swizzled) + khs
    for (int idx = tid; idx < 1024; idx += 128) {
        const int c = idx >> 4, sc = idx & 15;
        const int kq = sc ^ ((c >> 2) & 7);
        wq4[idx] = ((const float4*)Wq)[c * 16 + kq];
    }
    for (int idx = tid; idx < 128; idx += 128)
        ((float4*)khs_l)[idx] = ((const float4*)khs_g)[idx];

    const float4 bqlo = ((const float4*)bq)[cc];
    const float4 bqhi = ((const float4*)bq)[8 + cc];

    float zacc[8] = {};
    int cur_b = -1;

    // block-uniform call sites only
    auto flushz = [&](int b) {
        if (b < 0) return;
        #pragma unroll
        for (int jj = 0; jj < 8; ++jj) {
            zacc[jj] += __shfl_xor(zacc[jj], 8);
            zacc[jj] += __shfl_xor(zacc[jj], 16);
            zacc[jj] += __shfl_xor(zacc[jj], 32);
        }
        __syncthreads();                 // zred reuse guard
        if ((tid & 56) == 0) {           // one lane per (wave, cc)
            const int wv = tid >> 6;
            *(float4*)&zred[wv * 64 + 4 * cc] =
                make_float4(zacc[0], zacc[1], zacc[2], zacc[3]);
            *(float4*)&zred[wv * 64 + 32 + 4 * cc] =
                make_float4(zacc[4], zacc[5], zacc[6], zacc[7]);
        }
        __syncthreads();
        if (tid < 64) {
            float s = zred[tid] + zred[64 + tid];
            unsafeAtomicAdd(&zg[b * 64 + tid], (double)s);
        }
        #pragma unroll
        for (int jj = 0; jj < 8; ++jj) zacc[jj] = 0.f;
    };

    const int t0 = blockIdx.x * TPB;
    const int t1 = (t0 + TPB < NT128) ? (t0 + TPB) : NT128;

    SETUP_BASES();

    for (int t = t0; t < t1; ++t) {
        const int p0g = t * 128;
        stage_tile_async(q, t, qT, tid);            // async; drained at bar A
        const int b_lo = batch[p0g];
        const int b_hi = batch[(p0g + 127 < NPTS) ? (p0g + 127) : (NPTS - 1)];
        const bool uni = (b_lo == b_hi);
        __syncthreads();                            // bar A: tile + (first-iter) wq ready

        if (uni) {
            if (cur_b != b_lo) { flushz(cur_b); cur_b = b_lo; }
        } else {
            flushz(cur_b);
            cur_b = -1;
        }

        float acc[8][8] = {};
        GEMM88(qT4, wq4c);

        const int pbase = p0g + 8 * ty;
        if (uni) {
            const float4 klo = *(const float4*)&khs_l[b_lo * 64 + 4 * cc];
            const float4 khi = *(const float4*)&khs_l[b_lo * 64 + 32 + 4 * cc];
            #pragma unroll
            for (int i = 0; i < 8; ++i) {
                const int gp = pbase + i;
                if (gp < NPTS) {
                    float4 e0, e1;
                    e0.x = __expf((acc[i][0] + bqlo.x) * klo.x);
                    e0.y = __expf((acc[i][1] + bqlo.y) * klo.y);
                    e0.z = __expf((acc[i][2] + bqlo.z) * klo.z);
                    e0.w = __expf((acc[i][3] + bqlo.w) * klo.w);
                    e1.x = __expf((acc[i][4] + bqhi.x) * khi.x);
                    e1.y = __expf((acc[i][5] + bqhi.y) * khi.y);
                    e1.z = __expf((acc[i][6] + bqhi.z) * khi.z);
                    e1.w = __expf((acc[i][7] + bqhi.w) * khi.w);
                    ((float4*)e_out)[gp * 16 + cc]     = e0;
                    ((float4*)e_out)[gp * 16 + 8 + cc] = e1;
                    zacc[0] += e0.x; zacc[1] += e0.y; zacc[2] += e0.z; zacc[3] += e0.w;
                    zacc[4] += e1.x; zacc[5] += e1.y; zacc[6] += e1.z; zacc[7] += e1.w;
                }
            }
        } else {
            // rare boundary tile (<=7 in the whole grid)
            #pragma unroll
            for (int i = 0; i < 8; ++i) {
                const int gp = pbase + i;
                if (gp < NPTS) {
                    const int bi = batch[gp];
                    const float4 klo = *(const float4*)&khs_l[bi * 64 + 4 * cc];
                    const float4 khi = *(const float4*)&khs_l[bi * 64 + 32 + 4 * cc];
                    float4 e0, e1;
                    e0.x = __expf((acc[i][0] + bqlo.x) * klo.x);
                    e0.y = __expf((acc[i][1] + bqlo.y) * klo.y);
                    e0.z = __expf((acc[i][2] + bqlo.z) * klo.z);
                    e0.w = __expf((acc[i][3] + bqlo.w) * klo.w);
                    e1.x = __expf((acc[i][4] + bqhi.x) * khi.x);
                    e1.y = __expf((acc[i][5] + bqhi.y) * khi.y);
                    e1.z = __expf((acc[i][6] + bqhi.z) * khi.z);
                    e1.w = __expf((acc[i][7] + bqhi.w) * khi.w);
                    ((float4*)e_out)[gp * 16 + cc]     = e0;
                    ((float4*)e_out)[gp * 16 + 8 + cc] = e1;
                    unsafeAtomicAdd(&zg[bi * 64 + 4 * cc + 0], (double)e0.x);
                    unsafeAtomicAdd(&zg[bi * 64 + 4 * cc + 1], (double)e0.y);
                    unsafeAtomicAdd(&zg[bi * 64 + 4 * cc + 2], (double)e0.z);
                    unsafeAtomicAdd(&zg[bi * 64 + 4 * cc + 3], (double)e0.w);
                    unsafeAtomicAdd(&zg[bi * 64 + 32 + 4 * cc + 0], (double)e1.x);
                    unsafeAtomicAdd(&zg[bi * 64 + 32 + 4 * cc + 1], (double)e1.y);
                    unsafeAtomicAdd(&zg[bi * 64 + 32 + 4 * cc + 2], (double)e1.z);
                    unsafeAtomicAdd(&zg[bi * 64 + 32 + 4 * cc + 3], (double)e1.w);
                }
            }
        }
        __syncthreads();   // bar B: all reads of qT done; next stage may overwrite
    }
    flushz(cur_b);
}

// passB: out = (e * (vh/z)[batch]) @ Wo.T + bo ; e read from d_out, written in place.
// vh/z is folded into the W tile per segment (W'_b = Wo ∘ w_b), restaged on segment
// change (~once per block). Boundary tiles fold per-point in LDS instead.
__global__ __launch_bounds__(128, 2) void passB_kernel(const int* __restrict__ batch,
                                                       const float* __restrict__ bo,
                                                       const float* __restrict__ Wo,
                                                       const float* __restrict__ ws,
                                                       float* __restrict__ out) {
    __shared__ __align__(16) float tT[8192];
    __shared__ __align__(16) float wp[4096];
    __shared__ __align__(16) float w_l[512];

    const float* vh_g = ws + 8704;
    const double* zg  = (const double*)(ws + 9216);

    const int tid = threadIdx.x;
    const int cc  = tid & 7;
    const int ty  = tid >> 3;

    const float4* tT4c = (const float4*)tT;
    float4* tT4 = (float4*)tT;
    const float4* wp4c = (const float4*)wp;
    float4* wp4 = (float4*)wp;

    for (int idx = tid; idx < 512; idx += 128)
        w_l[idx] = (float)((double)vh_g[idx] / zg[idx]);

    const float4 bolo = ((const float4*)bo)[cc];
    const float4 bohi = ((const float4*)bo)[8 + cc];

    // stage W' = Wo (row c' over contraction c), folded by w_b (b>=0) or raw (b==-1)
    auto stage_wp = [&](int b) {
        for (int idx = tid; idx < 1024; idx += 128) {
            const int c2 = idx >> 4, sc = idx & 15;
            const int kq = sc ^ ((c2 >> 2) & 7);
            float4 wv4 = ((const float4*)Wo)[c2 * 16 + kq];
            if (b >= 0) {
                const float4 f = *(const float4*)&w_l[b * 64 + 4 * kq];
                wv4.x *= f.x; wv4.y *= f.y; wv4.z *= f.z; wv4.w *= f.w;
            }
            wp4[idx] = wv4;
        }
    };

    const int t0 = blockIdx.x * TPB;
    const int t1 = (t0 + TPB < NT128) ? (t0 + TPB) : NT128;

    SETUP_BASES();

    int wb_cur = -2;   // -2 unloaded, -1 raw, else folded for segment wb_cur
    __syncthreads();   // w_l ready (needed by stage_wp)

    for (int t = t0; t < t1; ++t) {
        const int p0g = t * 128;
        stage_tile_async(out, t, tT, tid);          // async e-tile load
        const int b_lo = batch[p0g];
        const int b_hi = batch[(p0g + 127 < NPTS) ? (p0g + 127) : (NPTS - 1)];
        const bool uni = (b_lo == b_hi);
        const int want = uni ? b_lo : -1;
        if (want != wb_cur) { stage_wp(want); wb_cur = want; }
        __syncthreads();                            // bar A: tile + W' ready

        if (!uni) {
            // rare boundary tile: fold e *= w[batch[p]] in place (thread = row)
            const int gp = p0g + tid;
            const int bi = batch[(gp < NPTS) ? gp : (NPTS - 1)];
            #pragma unroll
            for (int sc = 0; sc < 16; ++sc) {
                const int kq = sc ^ ((tid >> 3) & 7);
                float4 t4 = tT4[tid * 16 + sc];
                const float4 f = *(const float4*)&w_l[bi * 64 + 4 * kq];
                t4.x *= f.x; t4.y *= f.y; t4.z *= f.z; t4.w *= f.w;
                tT4[tid * 16 + sc] = t4;
            }
            __syncthreads();
        }

        float acc[8][8] = {};
        GEMM88(tT4c, wp4c);

        const int pbase = p0g + 8 * ty;
        #pragma unroll
        for (int i = 0; i < 8; ++i) {
            const int gp = pbase + i;
            if (gp < NPTS) {
                ((float4*)out)[gp * 16 + cc] =
                    make_float4(acc[i][0] + bolo.x, acc[i][1] + bolo.y,
                                acc[i][2] + bolo.z, acc[i][3] + bolo.w);
                ((float4*)out)[gp * 16 + 8 + cc] =
                    make_float4(acc[i][4] + bohi.x, acc[i][5] + bohi.y,
                                acc[i][6] + bohi.z, acc[i][7] + bohi.w);
            }
        }
        __syncthreads();   // bar B: all reads of tT done; next stage may overwrite
    }
}

extern "C" void kernel_launch(void* const* d_in, const int* in_sizes, int n_in,
                              void* d_out, int out_size, void* d_ws, size_t ws_size,
                              hipStream_t stream) {
    const float* q   = (const float*)d_in[0];
    const float* k   = (const float*)d_in[1];
    const float* v   = (const float*)d_in[2];
    const float* Wq  = (const float*)d_in[3];
    const float* bq  = (const float*)d_in[4];
    const float* Wk  = (const float*)d_in[5];
    const float* bk  = (const float*)d_in[6];
    const float* Wv  = (const float*)d_in[7];
    const float* bv  = (const float*)d_in[8];
    const float* Wo  = (const float*)d_in[9];
    const float* bo  = (const float*)d_in[10];
    const int*  batch = (const int*)d_in[11];
    float* out = (float*)d_out;
    float* ws  = (float*)d_ws;

    prep_kernel<<<8, 256, 0, stream>>>(k, v, Wk, bk, Wv, bv, ws);
    passA_kernel<<<GRID, 128, 0, stream>>>(q, batch, bq, Wq, ws, out);
    passB_kernel<<<GRID, 128, 0, stream>>>(batch, bo, Wo, ws, out);
}